// Round 14
// baseline (1347.718 us; speedup 1.0000x reference)
//
#include <hip/hip_runtime.h>
#include <math.h>

// GCN via CSR gather. CSR(dst) built with a two-level binned counting sort where
// node degrees are derived INSIDE the partition sort (lsortA LDS histogram) --
// no global deg atomics. All scattered writes stay in block-private windows
// (R4-R6: device-wide scattered stores cost a full 64B line each).
// 3x (register-tiled GEMM[+fused relu] -> gather-agg) -> mean-pool -> head -> softmax.
// h is bf16. Gather: wave-uniform edge indices (scalar csrw loads + readfirstlane
// byte offsets -> saddr h loads), tiered chunks 16/8/pred-8.
// GEMM: __launch_bounds__(256,4) caps VGPR at 128 (R13: unconstrained allocator
// hit 236 VGPR -> 9.7% occupancy -> 73us latency-bound; math itself is ~8us).
// N=100000 nodes, E=1.6M edges (+N self-loops folded into gather init), nhid=64.

__device__ __forceinline__ unsigned short f2bf(float f) {
    unsigned int u = __float_as_uint(f);
    u += 0x7fffu + ((u >> 16) & 1u);   // round-to-nearest-even
    return (unsigned short)(u >> 16);
}
__device__ __forceinline__ float bf2f(unsigned short u) {
    return __uint_as_float((unsigned int)u << 16);
}

__global__ void zero_kernel(float* __restrict__ a, int n) {
    int i = blockIdx.x * 256 + threadIdx.x;
    if (i < n) a[i] = 0.f;
}

// ---- binned counting sort: partition = dst>>9 (512 nodes), P<=256, 256 chunks ----

__global__ __launch_bounds__(256) void hist_kernel(const int* __restrict__ dst,
                                                   int* __restrict__ counts,
                                                   int E, int P, int C) {
    __shared__ int hist[256];
    int t = threadIdx.x, b = blockIdx.x;
    if (t < P) hist[t] = 0;
    __syncthreads();
    int beg = b * C, end = min(E, beg + C);
    for (int e = beg + t; e < end; e += 256)
        atomicAdd(&hist[dst[e] >> 9], 1);
    __syncthreads();
    if (t < P) counts[t * 256 + b] = hist[t];
}

__global__ __launch_bounds__(256) void pscan_kernel(const int* __restrict__ counts,
                                                    int* __restrict__ pbase,
                                                    int* __restrict__ rowptr,
                                                    int P, int N) {
    __shared__ int s[256];
    int t = threadIdx.x;
    int v = 0;
    if (t < P)
        for (int b = 0; b < 256; ++b) v += counts[t * 256 + b];
    s[t] = v;
    __syncthreads();
    for (int off = 1; off < 256; off <<= 1) {
        int u = (t >= off) ? s[t - off] : 0;
        __syncthreads();
        s[t] += u;
        __syncthreads();
    }
    if (t < P) pbase[t] = s[t] - v;
    if (t == 255) { pbase[P] = s[255]; rowptr[N] = s[255]; }
}

__global__ __launch_bounds__(256) void offs_kernel(const int* __restrict__ counts,
                                                   const int* __restrict__ pbase,
                                                   int* __restrict__ offs) {
    __shared__ int s[256];
    int t = threadIdx.x, p = blockIdx.x;
    int v = counts[p * 256 + t];
    s[t] = v;
    __syncthreads();
    for (int off = 1; off < 256; off <<= 1) {
        int u = (t >= off) ? s[t - off] : 0;
        __syncthreads();
        s[t] += u;
        __syncthreads();
    }
    offs[p * 256 + t] = pbase[p] + s[t] - v;
}

__global__ __launch_bounds__(256) void bin_kernel(const int* __restrict__ src,
                                                  const int* __restrict__ dst,
                                                  const int* __restrict__ offs,
                                                  unsigned int* __restrict__ binned,
                                                  int E, int P, int C) {
    __shared__ int cur[256];
    int t = threadIdx.x, b = blockIdx.x;
    if (t < P) cur[t] = offs[t * 256 + b];
    __syncthreads();
    int beg = b * C, end = min(E, beg + C);
    for (int e = beg + t; e < end; e += 256) {
        int d = dst[e], s = src[e];
        int pos = atomicAdd(&cur[d >> 9], 1);
        binned[pos] = ((unsigned int)s << 9) | (unsigned int)(d & 511);
    }
}

__global__ __launch_bounds__(512) void lsortA_kernel(const unsigned int* __restrict__ binned,
                                                     const int* __restrict__ pbase,
                                                     int* __restrict__ rowptr,
                                                     float* __restrict__ dinv, int N) {
    __shared__ int ldeg[512];
    __shared__ int s[512];
    int t = threadIdx.x, p = blockIdx.x;
    int lo = p << 9;
    ldeg[t] = 0;
    __syncthreads();
    int eBeg = pbase[p], eEnd = pbase[p + 1];
    for (int j = eBeg + t; j < eEnd; j += 512)
        atomicAdd(&ldeg[binned[j] & 511u], 1);
    __syncthreads();
    int v = ldeg[t];
    s[t] = v;
    __syncthreads();
    for (int off = 1; off < 512; off <<= 1) {
        int u = (t >= off) ? s[t - off] : 0;
        __syncthreads();
        s[t] += u;
        __syncthreads();
    }
    if (lo + t < N) {
        rowptr[lo + t] = eBeg + s[t] - v;
        dinv[lo + t] = rsqrtf((float)(v + 1));
    }
}

__global__ __launch_bounds__(256) void lsortB_kernel(const unsigned int* __restrict__ binned,
                                                     const int* __restrict__ pbase,
                                                     const int* __restrict__ rowptr,
                                                     const float* __restrict__ dinv,
                                                     float2* __restrict__ csrw, int N) {
    __shared__ int cur[512];
    __shared__ float sdi[512];
    int t = threadIdx.x, p = blockIdx.x;
    int lo = p << 9, hi = min(N, lo + 512);
    for (int i = t; i < hi - lo; i += 256) {
        cur[i] = rowptr[lo + i];
        sdi[i] = dinv[lo + i];
    }
    __syncthreads();
    int eBeg = pbase[p], eEnd = pbase[p + 1];
    for (int j = eBeg + t; j < eEnd; j += 256) {
        unsigned int v = binned[j];
        int s = (int)(v >> 9);
        int dl = (int)(v & 511u);
        int pos = atomicAdd(&cur[dl], 1);
        csrw[pos] = make_float2(__int_as_float(s << 7), dinv[s] * sdi[dl]);
    }
}

// H[N,64](bf16) = relu?(X)[N,FIN](fp32) @ W[FIN,64]. Register-tiled: 64x64 tile per
// block, 256 threads x 4x4 outputs. sX leading dim padded +4. fp32 acc, bf16 store.
// __launch_bounds__(256,4): min 4 waves/SIMD -> <=128 VGPR (R13: unconstrained
// went to 236 VGPR / 9.7% occupancy / latency-bound).
template <int FIN, bool RELU>
__global__ __launch_bounds__(256, 4) void gemm_kernel(const float* __restrict__ X,
                                                      const float* __restrict__ W,
                                                      unsigned short* __restrict__ H, int N) {
    constexpr int FINP = FIN + 4;
    __shared__ float sW[FIN * 64];
    __shared__ float sX[64 * FINP];
    int tid = threadIdx.x;
    for (int i = tid * 4; i < FIN * 64; i += 1024)
        *(float4*)&sW[i] = *(const float4*)&W[i];
    int rowBase = blockIdx.x * 64;
    for (int i = tid * 4; i < 64 * FIN; i += 1024) {
        int r = i / FIN, c = i - r * FIN;
        int gr = rowBase + r;
        float4 v = make_float4(0.f, 0.f, 0.f, 0.f);
        if (gr < N) {
            v = *(const float4*)&X[(long)gr * FIN + c];
            if (RELU) {
                v.x = fmaxf(v.x, 0.f); v.y = fmaxf(v.y, 0.f);
                v.z = fmaxf(v.z, 0.f); v.w = fmaxf(v.w, 0.f);
            }
        }
        *(float4*)&sX[r * FINP + c] = v;
    }
    __syncthreads();
    int tx = tid & 15;
    int ty = tid >> 4;
    float acc[4][4];
#pragma unroll
    for (int rr = 0; rr < 4; ++rr)
#pragma unroll
        for (int cc = 0; cc < 4; ++cc) acc[rr][cc] = 0.f;
    for (int k = 0; k < FIN; k += 4) {
        float xr[4][4], wr[4][4];
#pragma unroll
        for (int rr = 0; rr < 4; ++rr)
            *(float4*)xr[rr] = *(const float4*)&sX[(ty + 16 * rr) * FINP + k];
#pragma unroll
        for (int kk = 0; kk < 4; ++kk)
            *(float4*)wr[kk] = *(const float4*)&sW[(k + kk) * 64 + 4 * tx];
#pragma unroll
        for (int rr = 0; rr < 4; ++rr)
#pragma unroll
            for (int kk = 0; kk < 4; ++kk)
#pragma unroll
                for (int cc = 0; cc < 4; ++cc)
                    acc[rr][cc] = fmaf(xr[rr][kk], wr[kk][cc], acc[rr][cc]);
    }
#pragma unroll
    for (int rr = 0; rr < 4; ++rr) {
        int gr = rowBase + ty + 16 * rr;
        if (gr < N) {
            ushort4 o;
            o.x = f2bf(acc[rr][0]); o.y = f2bf(acc[rr][1]);
            o.z = f2bf(acc[rr][2]); o.w = f2bf(acc[rr][3]);
            *(ushort4*)&H[(long)gr * 64 + 4 * tx] = o;
        }
    }
}

// Gather v5: one wave per dst node, lane = feature column (bf16 row = 128B).
// Wave-uniform edge indices; readfirstlane byte offsets -> saddr h loads.
// Tiered chunks: full-16, full-8, one predicated-8 (uniform clamp, no serial tail).
__global__ __launch_bounds__(256) void gather_kernel(const float2* __restrict__ csrw,
                                                     const int* __restrict__ rowptr,
                                                     const unsigned short* __restrict__ h,
                                                     const float* __restrict__ dinv,
                                                     const float* __restrict__ b,
                                                     float* __restrict__ agg, int N) {
    int node = (blockIdx.x * 256 + threadIdx.x) >> 6;
    int lane = threadIdx.x & 63;
    if (node >= N) return;
    int beg = rowptr[node], end = rowptr[node + 1];
    float di = dinv[node];
    float a[8];
    a[0] = fmaf(di * di, bf2f(h[(long)node * 64 + lane]), b[lane]);
#pragma unroll
    for (int j = 1; j < 8; ++j) a[j] = 0.f;

    const char* hb = (const char*)h;
    int e = beg;
    while (e + 16 <= end) {
        float2 c[16];
#pragma unroll
        for (int j = 0; j < 16; ++j) c[j] = csrw[e + j];
#pragma unroll
        for (int j = 0; j < 16; ++j) {
            int offb = __builtin_amdgcn_readfirstlane(__float_as_int(c[j].x));
            const unsigned short* hp = (const unsigned short*)(hb + offb);
            a[j & 7] = fmaf(c[j].y, bf2f(hp[lane]), a[j & 7]);
        }
        e += 16;
    }
    if (e + 8 <= end) {
        float2 c[8];
#pragma unroll
        for (int j = 0; j < 8; ++j) c[j] = csrw[e + j];
#pragma unroll
        for (int j = 0; j < 8; ++j) {
            int offb = __builtin_amdgcn_readfirstlane(__float_as_int(c[j].x));
            const unsigned short* hp = (const unsigned short*)(hb + offb);
            a[j] = fmaf(c[j].y, bf2f(hp[lane]), a[j]);
        }
        e += 8;
    }
    if (e < end) {   // one predicated chunk, wave-uniform clamp
#pragma unroll
        for (int j = 0; j < 8; ++j) {
            int idx = e + j;
            float2 c = csrw[idx < end ? idx : end - 1];
            float w = idx < end ? c.y : 0.f;
            int offb = __builtin_amdgcn_readfirstlane(__float_as_int(c.x));
            const unsigned short* hp = (const unsigned short*)(hb + offb);
            a[j] = fmaf(w, bf2f(hp[lane]), a[j]);
        }
    }
    agg[(long)node * 64 + lane] =
        ((a[0] + a[1]) + (a[2] + a[3])) + ((a[4] + a[5]) + (a[6] + a[7]));
}

// batch is sorted: one WAVE per 64 contiguous nodes (lane = col), running accumulation
// with flush on graph change; col==0 lane flushes run-length counts; fused relu.
__global__ __launch_bounds__(256) void pool_kernel(const float* __restrict__ h,
                                                   const int* __restrict__ batch,
                                                   float* __restrict__ sums,
                                                   float* __restrict__ cnts, int N) {
    int col = threadIdx.x & 63;
    int wave = threadIdx.x >> 6;
    int base = blockIdx.x * 256 + wave * 64;
    float acc = 0.f, cnt = 0.f;
    int curg = -1;
    for (int j = 0; j < 64; ++j) {
        int node = base + j;
        if (node >= N) break;
        int g = batch[node];
        if (g != curg) {
            if (curg >= 0) {
                atomicAdd(&sums[curg * 64 + col], acc);
                if (col == 0) atomicAdd(&cnts[curg], cnt);
            }
            acc = 0.f; cnt = 0.f;
            curg = g;
        }
        acc += fmaxf(h[(long)node * 64 + col], 0.f);
        cnt += 1.f;
    }
    if (curg >= 0) {
        atomicAdd(&sums[curg * 64 + col], acc);
        if (col == 0) atomicAdd(&cnts[curg], cnt);
    }
}

// One thread per graph: pooled = sums/cnt, logits = pooled @ Wl + bl, softmax.
__global__ void final_kernel(const float* __restrict__ sums, const float* __restrict__ cnts,
                             const float* __restrict__ Wl, const float* __restrict__ bl,
                             float* __restrict__ out, int G) {
    int g = blockIdx.x * blockDim.x + threadIdx.x;
    if (g >= G) return;
    float inv = 1.0f / fmaxf(cnts[g], 1.0f);
    float logits[10];
#pragma unroll
    for (int k = 0; k < 10; ++k) logits[k] = bl[k];
    for (int c = 0; c < 64; ++c) {
        float p = sums[g * 64 + c] * inv;
#pragma unroll
        for (int k = 0; k < 10; ++k) logits[k] = fmaf(p, Wl[c * 10 + k], logits[k]);
    }
    float m = logits[0];
#pragma unroll
    for (int k = 1; k < 10; ++k) m = fmaxf(m, logits[k]);
    float se = 0.f;
#pragma unroll
    for (int k = 0; k < 10; ++k) { logits[k] = expf(logits[k] - m); se += logits[k]; }
    float is = 1.0f / se;
#pragma unroll
    for (int k = 0; k < 10; ++k) out[g * 10 + k] = logits[k] * is;
}

extern "C" void kernel_launch(void* const* d_in, const int* in_sizes, int n_in,
                              void* d_out, int out_size, void* d_ws, size_t ws_size,
                              hipStream_t stream) {
    const float* x    = (const float*)d_in[0];
    const int* edges  = (const int*)d_in[1];
    const int* batch  = (const int*)d_in[2];
    const float* W1   = (const float*)d_in[3];
    const float* b1   = (const float*)d_in[4];
    const float* W2   = (const float*)d_in[5];
    const float* b2   = (const float*)d_in[6];
    const float* W3   = (const float*)d_in[7];
    const float* b3   = (const float*)d_in[8];
    const float* Wl   = (const float*)d_in[9];
    const float* bl   = (const float*)d_in[10];

    const int N = in_sizes[0] / 128;   // 100000
    const int E = in_sizes[1] / 2;     // 1600000
    const int G = out_size / 10;       // 64
    const int* src = edges;
    const int* dst = edges + E;

    float* ws     = (float*)d_ws;
    unsigned short* h = (unsigned short*)ws;      // N*64 bf16 (slot reserves N*64 floats)
    float* agg    = ws + (size_t)N * 64;          // N*64 fp32
    unsigned int* binned = (unsigned int*)ws;     // E uint ALIASES h slot: dead before gemm1
    float2* csrw  = (float2*)(ws + (size_t)2 * N * 64);  // E float2 {src_byte_off, w}
    float* dinv   = ws + (size_t)2 * N * 64 + (size_t)2 * E;  // N
    int*   rowptr = (int*)(dinv + N);             // N+1
    int*   counts = rowptr + N + 1;               // 256*256
    int*   offs   = counts + 256 * 256;           // 256*256
    int*   pbase  = offs + 256 * 256;             // P+1 <= 257
    float* sums   = (float*)(pbase + 257);        // G*64
    float* cnts   = sums + (size_t)G * 64;        // G

    const int gemmGrid = (N + 63) / 64;
    const int gatherGrid = (N + 3) / 4;
    const int P = (N + 511) >> 9;                 // 196 partitions of 512 nodes
    const int C = (E + 255) / 256;                // edges per chunk (256 chunks)

    // binned counting sort -> rowptr/dinv (lsortA) + csrw {src_byte_off, w} (lsortB)
    hist_kernel<<<256, 256, 0, stream>>>(dst, counts, E, P, C);
    pscan_kernel<<<1, 256, 0, stream>>>(counts, pbase, rowptr, P, N);
    offs_kernel<<<P, 256, 0, stream>>>(counts, pbase, offs);
    bin_kernel<<<256, 256, 0, stream>>>(src, dst, offs, binned, E, P, C);
    lsortA_kernel<<<P, 512, 0, stream>>>(binned, pbase, rowptr, dinv, N);
    lsortB_kernel<<<P, 256, 0, stream>>>(binned, pbase, rowptr, dinv, csrw, N);

    // layer 1: x[N,128] @ W1 -> h bf16 (overwrites binned; build complete); gather
    gemm_kernel<128, false><<<gemmGrid, 256, 0, stream>>>(x, W1, h, N);
    gather_kernel<<<gatherGrid, 256, 0, stream>>>(csrw, rowptr, h, dinv, b1, agg, N);

    // layer 2 (relu of layer-1 output fused into gemm's X load)
    gemm_kernel<64, true><<<gemmGrid, 256, 0, stream>>>(agg, W2, h, N);
    gather_kernel<<<gatherGrid, 256, 0, stream>>>(csrw, rowptr, h, dinv, b2, agg, N);

    // layer 3
    gemm_kernel<64, true><<<gemmGrid, 256, 0, stream>>>(agg, W3, h, N);
    gather_kernel<<<gatherGrid, 256, 0, stream>>>(csrw, rowptr, h, dinv, b3, agg, N);

    // mean-pool per graph (+count, +fused relu) + head + softmax
    zero_kernel<<<(G * 65 + 255) / 256, 256, 0, stream>>>(sums, G * 65);
    pool_kernel<<<(N + 255) / 256, 256, 0, stream>>>(agg, batch, sums, cnts, N);
    final_kernel<<<1, 64, 0, stream>>>(sums, cnts, Wl, bl, (float*)d_out, G);
}

// Round 15
// 462.724 us; speedup vs baseline: 2.9126x; 2.9126x over previous
//
#include <hip/hip_runtime.h>
#include <math.h>

// GCN via CSR gather. CSR(dst) built with a two-level binned counting sort where
// node degrees are derived INSIDE the partition sort (lsortA LDS histogram) --
// no global deg atomics. All scattered writes stay in block-private windows
// (R4-R6: device-wide scattered stores cost a full 64B line each).
// 3x (register-tiled GEMM[+fused relu] -> gather-agg) -> mean-pool -> head -> softmax.
// h is bf16. Gather: wave-uniform edge indices (scalar csrw loads + readfirstlane
// byte offsets -> saddr h loads), tiered chunks 16/8/pred-8.
// GEMM register pressure: R13 showed auto-unrolled k-loop -> 236 VGPR / 9.7% occ;
// R14 showed __launch_bounds__(256,4) forces SPILLS (547MB scratch writes, 2.6x
// slower). Fix at source: #pragma unroll 1 on the k-loop (live set ~70-90 VGPR),
// NO launch-bounds cap.
// N=100000 nodes, E=1.6M edges (+N self-loops folded into gather init), nhid=64.

__device__ __forceinline__ unsigned short f2bf(float f) {
    unsigned int u = __float_as_uint(f);
    u += 0x7fffu + ((u >> 16) & 1u);   // round-to-nearest-even
    return (unsigned short)(u >> 16);
}
__device__ __forceinline__ float bf2f(unsigned short u) {
    return __uint_as_float((unsigned int)u << 16);
}

__global__ void zero_kernel(float* __restrict__ a, int n) {
    int i = blockIdx.x * 256 + threadIdx.x;
    if (i < n) a[i] = 0.f;
}

// ---- binned counting sort: partition = dst>>9 (512 nodes), P<=256, 256 chunks ----

__global__ __launch_bounds__(256) void hist_kernel(const int* __restrict__ dst,
                                                   int* __restrict__ counts,
                                                   int E, int P, int C) {
    __shared__ int hist[256];
    int t = threadIdx.x, b = blockIdx.x;
    if (t < P) hist[t] = 0;
    __syncthreads();
    int beg = b * C, end = min(E, beg + C);
    for (int e = beg + t; e < end; e += 256)
        atomicAdd(&hist[dst[e] >> 9], 1);
    __syncthreads();
    if (t < P) counts[t * 256 + b] = hist[t];
}

__global__ __launch_bounds__(256) void pscan_kernel(const int* __restrict__ counts,
                                                    int* __restrict__ pbase,
                                                    int* __restrict__ rowptr,
                                                    int P, int N) {
    __shared__ int s[256];
    int t = threadIdx.x;
    int v = 0;
    if (t < P)
        for (int b = 0; b < 256; ++b) v += counts[t * 256 + b];
    s[t] = v;
    __syncthreads();
    for (int off = 1; off < 256; off <<= 1) {
        int u = (t >= off) ? s[t - off] : 0;
        __syncthreads();
        s[t] += u;
        __syncthreads();
    }
    if (t < P) pbase[t] = s[t] - v;
    if (t == 255) { pbase[P] = s[255]; rowptr[N] = s[255]; }
}

__global__ __launch_bounds__(256) void offs_kernel(const int* __restrict__ counts,
                                                   const int* __restrict__ pbase,
                                                   int* __restrict__ offs) {
    __shared__ int s[256];
    int t = threadIdx.x, p = blockIdx.x;
    int v = counts[p * 256 + t];
    s[t] = v;
    __syncthreads();
    for (int off = 1; off < 256; off <<= 1) {
        int u = (t >= off) ? s[t - off] : 0;
        __syncthreads();
        s[t] += u;
        __syncthreads();
    }
    offs[p * 256 + t] = pbase[p] + s[t] - v;
}

__global__ __launch_bounds__(256) void bin_kernel(const int* __restrict__ src,
                                                  const int* __restrict__ dst,
                                                  const int* __restrict__ offs,
                                                  unsigned int* __restrict__ binned,
                                                  int E, int P, int C) {
    __shared__ int cur[256];
    int t = threadIdx.x, b = blockIdx.x;
    if (t < P) cur[t] = offs[t * 256 + b];
    __syncthreads();
    int beg = b * C, end = min(E, beg + C);
    for (int e = beg + t; e < end; e += 256) {
        int d = dst[e], s = src[e];
        int pos = atomicAdd(&cur[d >> 9], 1);
        binned[pos] = ((unsigned int)s << 9) | (unsigned int)(d & 511);
    }
}

__global__ __launch_bounds__(512) void lsortA_kernel(const unsigned int* __restrict__ binned,
                                                     const int* __restrict__ pbase,
                                                     int* __restrict__ rowptr,
                                                     float* __restrict__ dinv, int N) {
    __shared__ int ldeg[512];
    __shared__ int s[512];
    int t = threadIdx.x, p = blockIdx.x;
    int lo = p << 9;
    ldeg[t] = 0;
    __syncthreads();
    int eBeg = pbase[p], eEnd = pbase[p + 1];
    for (int j = eBeg + t; j < eEnd; j += 512)
        atomicAdd(&ldeg[binned[j] & 511u], 1);
    __syncthreads();
    int v = ldeg[t];
    s[t] = v;
    __syncthreads();
    for (int off = 1; off < 512; off <<= 1) {
        int u = (t >= off) ? s[t - off] : 0;
        __syncthreads();
        s[t] += u;
        __syncthreads();
    }
    if (lo + t < N) {
        rowptr[lo + t] = eBeg + s[t] - v;
        dinv[lo + t] = rsqrtf((float)(v + 1));
    }
}

__global__ __launch_bounds__(256) void lsortB_kernel(const unsigned int* __restrict__ binned,
                                                     const int* __restrict__ pbase,
                                                     const int* __restrict__ rowptr,
                                                     const float* __restrict__ dinv,
                                                     float2* __restrict__ csrw, int N) {
    __shared__ int cur[512];
    __shared__ float sdi[512];
    int t = threadIdx.x, p = blockIdx.x;
    int lo = p << 9, hi = min(N, lo + 512);
    for (int i = t; i < hi - lo; i += 256) {
        cur[i] = rowptr[lo + i];
        sdi[i] = dinv[lo + i];
    }
    __syncthreads();
    int eBeg = pbase[p], eEnd = pbase[p + 1];
    for (int j = eBeg + t; j < eEnd; j += 256) {
        unsigned int v = binned[j];
        int s = (int)(v >> 9);
        int dl = (int)(v & 511u);
        int pos = atomicAdd(&cur[dl], 1);
        csrw[pos] = make_float2(__int_as_float(s << 7), dinv[s] * sdi[dl]);
    }
}

// H[N,64](bf16) = relu?(X)[N,FIN](fp32) @ W[FIN,64]. Register-tiled: 64x64 tile per
// block, 256 threads x 4x4 outputs. sX leading dim padded +4. fp32 acc, bf16 store.
// k-loop pinned at unroll 1: live set = acc16+xr16+wr16 (~90 VGPR), no spills.
template <int FIN, bool RELU>
__global__ __launch_bounds__(256) void gemm_kernel(const float* __restrict__ X,
                                                   const float* __restrict__ W,
                                                   unsigned short* __restrict__ H, int N) {
    constexpr int FINP = FIN + 4;
    __shared__ float sW[FIN * 64];
    __shared__ float sX[64 * FINP];
    int tid = threadIdx.x;
    for (int i = tid * 4; i < FIN * 64; i += 1024)
        *(float4*)&sW[i] = *(const float4*)&W[i];
    int rowBase = blockIdx.x * 64;
    for (int i = tid * 4; i < 64 * FIN; i += 1024) {
        int r = i / FIN, c = i - r * FIN;
        int gr = rowBase + r;
        float4 v = make_float4(0.f, 0.f, 0.f, 0.f);
        if (gr < N) {
            v = *(const float4*)&X[(long)gr * FIN + c];
            if (RELU) {
                v.x = fmaxf(v.x, 0.f); v.y = fmaxf(v.y, 0.f);
                v.z = fmaxf(v.z, 0.f); v.w = fmaxf(v.w, 0.f);
            }
        }
        *(float4*)&sX[r * FINP + c] = v;
    }
    __syncthreads();
    int tx = tid & 15;
    int ty = tid >> 4;
    float acc[4][4];
#pragma unroll
    for (int rr = 0; rr < 4; ++rr)
#pragma unroll
        for (int cc = 0; cc < 4; ++cc) acc[rr][cc] = 0.f;
#pragma unroll 1
    for (int k = 0; k < FIN; k += 4) {
        float xr[4][4], wr[4][4];
#pragma unroll
        for (int rr = 0; rr < 4; ++rr)
            *(float4*)xr[rr] = *(const float4*)&sX[(ty + 16 * rr) * FINP + k];
#pragma unroll
        for (int kk = 0; kk < 4; ++kk)
            *(float4*)wr[kk] = *(const float4*)&sW[(k + kk) * 64 + 4 * tx];
#pragma unroll
        for (int rr = 0; rr < 4; ++rr)
#pragma unroll
            for (int kk = 0; kk < 4; ++kk)
#pragma unroll
                for (int cc = 0; cc < 4; ++cc)
                    acc[rr][cc] = fmaf(xr[rr][kk], wr[kk][cc], acc[rr][cc]);
    }
#pragma unroll
    for (int rr = 0; rr < 4; ++rr) {
        int gr = rowBase + ty + 16 * rr;
        if (gr < N) {
            ushort4 o;
            o.x = f2bf(acc[rr][0]); o.y = f2bf(acc[rr][1]);
            o.z = f2bf(acc[rr][2]); o.w = f2bf(acc[rr][3]);
            *(ushort4*)&H[(long)gr * 64 + 4 * tx] = o;
        }
    }
}

// Gather v5: one wave per dst node, lane = feature column (bf16 row = 128B).
// Wave-uniform edge indices; readfirstlane byte offsets -> saddr h loads.
// Tiered chunks: full-16, full-8, one predicated-8 (uniform clamp, no serial tail).
__global__ __launch_bounds__(256) void gather_kernel(const float2* __restrict__ csrw,
                                                     const int* __restrict__ rowptr,
                                                     const unsigned short* __restrict__ h,
                                                     const float* __restrict__ dinv,
                                                     const float* __restrict__ b,
                                                     float* __restrict__ agg, int N) {
    int node = (blockIdx.x * 256 + threadIdx.x) >> 6;
    int lane = threadIdx.x & 63;
    if (node >= N) return;
    int beg = rowptr[node], end = rowptr[node + 1];
    float di = dinv[node];
    float a[8];
    a[0] = fmaf(di * di, bf2f(h[(long)node * 64 + lane]), b[lane]);
#pragma unroll
    for (int j = 1; j < 8; ++j) a[j] = 0.f;

    const char* hb = (const char*)h;
    int e = beg;
    while (e + 16 <= end) {
        float2 c[16];
#pragma unroll
        for (int j = 0; j < 16; ++j) c[j] = csrw[e + j];
#pragma unroll
        for (int j = 0; j < 16; ++j) {
            int offb = __builtin_amdgcn_readfirstlane(__float_as_int(c[j].x));
            const unsigned short* hp = (const unsigned short*)(hb + offb);
            a[j & 7] = fmaf(c[j].y, bf2f(hp[lane]), a[j & 7]);
        }
        e += 16;
    }
    if (e + 8 <= end) {
        float2 c[8];
#pragma unroll
        for (int j = 0; j < 8; ++j) c[j] = csrw[e + j];
#pragma unroll
        for (int j = 0; j < 8; ++j) {
            int offb = __builtin_amdgcn_readfirstlane(__float_as_int(c[j].x));
            const unsigned short* hp = (const unsigned short*)(hb + offb);
            a[j] = fmaf(c[j].y, bf2f(hp[lane]), a[j]);
        }
        e += 8;
    }
    if (e < end) {   // one predicated chunk, wave-uniform clamp
#pragma unroll
        for (int j = 0; j < 8; ++j) {
            int idx = e + j;
            float2 c = csrw[idx < end ? idx : end - 1];
            float w = idx < end ? c.y : 0.f;
            int offb = __builtin_amdgcn_readfirstlane(__float_as_int(c.x));
            const unsigned short* hp = (const unsigned short*)(hb + offb);
            a[j] = fmaf(w, bf2f(hp[lane]), a[j]);
        }
    }
    agg[(long)node * 64 + lane] =
        ((a[0] + a[1]) + (a[2] + a[3])) + ((a[4] + a[5]) + (a[6] + a[7]));
}

// batch is sorted: one WAVE per 64 contiguous nodes (lane = col), running accumulation
// with flush on graph change; col==0 lane flushes run-length counts; fused relu.
__global__ __launch_bounds__(256) void pool_kernel(const float* __restrict__ h,
                                                   const int* __restrict__ batch,
                                                   float* __restrict__ sums,
                                                   float* __restrict__ cnts, int N) {
    int col = threadIdx.x & 63;
    int wave = threadIdx.x >> 6;
    int base = blockIdx.x * 256 + wave * 64;
    float acc = 0.f, cnt = 0.f;
    int curg = -1;
    for (int j = 0; j < 64; ++j) {
        int node = base + j;
        if (node >= N) break;
        int g = batch[node];
        if (g != curg) {
            if (curg >= 0) {
                atomicAdd(&sums[curg * 64 + col], acc);
                if (col == 0) atomicAdd(&cnts[curg], cnt);
            }
            acc = 0.f; cnt = 0.f;
            curg = g;
        }
        acc += fmaxf(h[(long)node * 64 + col], 0.f);
        cnt += 1.f;
    }
    if (curg >= 0) {
        atomicAdd(&sums[curg * 64 + col], acc);
        if (col == 0) atomicAdd(&cnts[curg], cnt);
    }
}

// One thread per graph: pooled = sums/cnt, logits = pooled @ Wl + bl, softmax.
__global__ void final_kernel(const float* __restrict__ sums, const float* __restrict__ cnts,
                             const float* __restrict__ Wl, const float* __restrict__ bl,
                             float* __restrict__ out, int G) {
    int g = blockIdx.x * blockDim.x + threadIdx.x;
    if (g >= G) return;
    float inv = 1.0f / fmaxf(cnts[g], 1.0f);
    float logits[10];
#pragma unroll
    for (int k = 0; k < 10; ++k) logits[k] = bl[k];
    for (int c = 0; c < 64; ++c) {
        float p = sums[g * 64 + c] * inv;
#pragma unroll
        for (int k = 0; k < 10; ++k) logits[k] = fmaf(p, Wl[c * 10 + k], logits[k]);
    }
    float m = logits[0];
#pragma unroll
    for (int k = 1; k < 10; ++k) m = fmaxf(m, logits[k]);
    float se = 0.f;
#pragma unroll
    for (int k = 0; k < 10; ++k) { logits[k] = expf(logits[k] - m); se += logits[k]; }
    float is = 1.0f / se;
#pragma unroll
    for (int k = 0; k < 10; ++k) out[g * 10 + k] = logits[k] * is;
}

extern "C" void kernel_launch(void* const* d_in, const int* in_sizes, int n_in,
                              void* d_out, int out_size, void* d_ws, size_t ws_size,
                              hipStream_t stream) {
    const float* x    = (const float*)d_in[0];
    const int* edges  = (const int*)d_in[1];
    const int* batch  = (const int*)d_in[2];
    const float* W1   = (const float*)d_in[3];
    const float* b1   = (const float*)d_in[4];
    const float* W2   = (const float*)d_in[5];
    const float* b2   = (const float*)d_in[6];
    const float* W3   = (const float*)d_in[7];
    const float* b3   = (const float*)d_in[8];
    const float* Wl   = (const float*)d_in[9];
    const float* bl   = (const float*)d_in[10];

    const int N = in_sizes[0] / 128;   // 100000
    const int E = in_sizes[1] / 2;     // 1600000
    const int G = out_size / 10;       // 64
    const int* src = edges;
    const int* dst = edges + E;

    float* ws     = (float*)d_ws;
    unsigned short* h = (unsigned short*)ws;      // N*64 bf16 (slot reserves N*64 floats)
    float* agg    = ws + (size_t)N * 64;          // N*64 fp32
    unsigned int* binned = (unsigned int*)ws;     // E uint ALIASES h slot: dead before gemm1
    float2* csrw  = (float2*)(ws + (size_t)2 * N * 64);  // E float2 {src_byte_off, w}
    float* dinv   = ws + (size_t)2 * N * 64 + (size_t)2 * E;  // N
    int*   rowptr = (int*)(dinv + N);             // N+1
    int*   counts = rowptr + N + 1;               // 256*256
    int*   offs   = counts + 256 * 256;           // 256*256
    int*   pbase  = offs + 256 * 256;             // P+1 <= 257
    float* sums   = (float*)(pbase + 257);        // G*64
    float* cnts   = sums + (size_t)G * 64;        // G

    const int gemmGrid = (N + 63) / 64;
    const int gatherGrid = (N + 3) / 4;
    const int P = (N + 511) >> 9;                 // 196 partitions of 512 nodes
    const int C = (E + 255) / 256;                // edges per chunk (256 chunks)

    // binned counting sort -> rowptr/dinv (lsortA) + csrw {src_byte_off, w} (lsortB)
    hist_kernel<<<256, 256, 0, stream>>>(dst, counts, E, P, C);
    pscan_kernel<<<1, 256, 0, stream>>>(counts, pbase, rowptr, P, N);
    offs_kernel<<<P, 256, 0, stream>>>(counts, pbase, offs);
    bin_kernel<<<256, 256, 0, stream>>>(src, dst, offs, binned, E, P, C);
    lsortA_kernel<<<P, 512, 0, stream>>>(binned, pbase, rowptr, dinv, N);
    lsortB_kernel<<<P, 256, 0, stream>>>(binned, pbase, rowptr, dinv, csrw, N);

    // layer 1: x[N,128] @ W1 -> h bf16 (overwrites binned; build complete); gather
    gemm_kernel<128, false><<<gemmGrid, 256, 0, stream>>>(x, W1, h, N);
    gather_kernel<<<gatherGrid, 256, 0, stream>>>(csrw, rowptr, h, dinv, b1, agg, N);

    // layer 2 (relu of layer-1 output fused into gemm's X load)
    gemm_kernel<64, true><<<gemmGrid, 256, 0, stream>>>(agg, W2, h, N);
    gather_kernel<<<gatherGrid, 256, 0, stream>>>(csrw, rowptr, h, dinv, b2, agg, N);

    // layer 3
    gemm_kernel<64, true><<<gemmGrid, 256, 0, stream>>>(agg, W3, h, N);
    gather_kernel<<<gatherGrid, 256, 0, stream>>>(csrw, rowptr, h, dinv, b3, agg, N);

    // mean-pool per graph (+count, +fused relu) + head + softmax
    zero_kernel<<<(G * 65 + 255) / 256, 256, 0, stream>>>(sums, G * 65);
    pool_kernel<<<(N + 255) / 256, 256, 0, stream>>>(agg, batch, sums, cnts, N);
    final_kernel<<<1, 64, 0, stream>>>(sums, cnts, Wl, bl, (float*)d_out, G);
}